// Round 2
// baseline (1845.085 us; speedup 1.0000x reference)
//
#include <hip/hip_runtime.h>
#include <hip/hip_bf16.h>

// ---------------------------------------------------------------------------
// CANDY_41077067219071: out = p_out + z_out where
//   t     = Wp_eff @ (x * act(p_mask))          (per channel, 1024^3)
//   p_out = act(act(t) @ p_lin_w^T + b_p)
//   z     = Wzp @ p_out
//   z_out = act(act(z) @ z_lin_w^T + b_z)
// act(v) = clamp(v,-1,1).  All GEMMs as TN bf16 MFMA 16x16x32, 128x128 tiles,
// BK=32, global_load_lds(16B) staging, XOR-swizzled LDS (2-way aliasing only).
// mm1/mm3 use hi/lo bf16 split (3 MFMA products) for ~17-bit mantissa; mm2/mm4
// plain bf16.  mm2/mm4 computed transposed (C'[j,h]) so every operand stays
// K-contiguous; final f32 transpose restores [c][h][j].  mm1 skips k-tiles
// above the diagonal (Wp_eff is tril + diag).
// OUTPUT IS FLOAT32 (reference returns jnp.float32) — round-1 post-mortem:
// bf16 writes read as f32 gave the 4.0156 absmax signature.
// Workspace layout (needs ~652 MiB):
//   [0,256M)    pSetT hi + lo (2 x 128M)  -> reused as f32 outT after mm1
//   [256,384M)  pT hi
//   [384,512M)  pT lo
//   [512,640M)  tA (act_t bf16; reused for act_z after mm2)
//   [640M,...)  weight splits (6 x 2 MiB)
// ---------------------------------------------------------------------------

typedef short bf16x8 __attribute__((ext_vector_type(8)));
typedef float f32x4  __attribute__((ext_vector_type(4)));

__device__ __forceinline__ float actf(float v) { return fminf(1.f, fmaxf(-1.f, v)); }

__device__ __forceinline__ unsigned short f2bf(float f) {
    union { __hip_bfloat16 b; unsigned short u; } cv;
    cv.b = __float2bfloat16(f);
    return cv.u;
}
__device__ __forceinline__ float bf2f(unsigned short u) {
    union { unsigned short u; __hip_bfloat16 b; } cv;
    cv.u = u;
    return __bfloat162float(cv.b);
}

// logical 16B chunk q of row r lives at physical chunk q ^ swz(r)
__device__ __forceinline__ int swz(int r) { return (r ^ (r >> 2)) & 3; }

// Stage a 128x32 bf16 tile (rows row0.., cols k0..k0+31) of a K-contiguous
// matrix (row stride 1024 elems) into LDS via global_load_lds, 16B/lane.
__device__ __forceinline__ void stage_tile(const unsigned short* __restrict__ g,
                                           int row0, int k0,
                                           unsigned short* ldsBase, int t) {
    const int wave = t >> 6;
#pragma unroll
    for (int s = 0; s < 2; ++s) {
        const int ci = s * 256 + t;       // chunk index 0..511 (128 rows x 4)
        const int r  = ci >> 2;
        const int pc = ci & 3;            // physical chunk within row
        const int q  = pc ^ swz(r);       // logical chunk fetched from global
        const unsigned short* gsrc = g + ((size_t)(row0 + r) << 10) + k0 + q * 8;
        unsigned short* ldst = ldsBase + (size_t)(s * 256 + wave * 64) * 8; // wave-uniform
        __builtin_amdgcn_global_load_lds((const __attribute__((address_space(1))) void*)gsrc,
                                         (__attribute__((address_space(3))) void*)ldst,
                                         16, 0, 0);
    }
}

__device__ __forceinline__ bf16x8 read_frag(const unsigned short* ldsBase, int row, int q) {
    const int pc = q ^ swz(row);
    return *(const bf16x8*)(ldsBase + row * 32 + pc * 8);
}

// EPI 0: O1 = bf16(act(acc))
// EPI 1: v = act(acc + bias[m]); O1 = hi(v), O2 = lo(v)
// EPI 2: v = act(acc + bias[m]) + (Phi+Plo)[off]; Of = v   (FLOAT32 store)
template <bool SPLIT, int EPI, bool TRIL>
__global__ __launch_bounds__(256)
void gemm_tn(const unsigned short* __restrict__ Ahi,
             const unsigned short* __restrict__ Alo,
             const unsigned short* __restrict__ Bhi,
             const unsigned short* __restrict__ Blo,
             const float* __restrict__ bias,
             const unsigned short* __restrict__ Phi,
             const unsigned short* __restrict__ Plo,
             unsigned short* __restrict__ O1,
             unsigned short* __restrict__ O2,
             float* __restrict__ Of) {
    __shared__ __align__(16) unsigned short lds[(SPLIT ? 4 : 2) * 4096];
    unsigned short* ldsAhi = lds;
    unsigned short* ldsBhi = lds + 4096;
    unsigned short* ldsAlo = lds + (SPLIT ? 8192 : 0);
    unsigned short* ldsBlo = lds + (SPLIT ? 12288 : 0);

    const int t    = threadIdx.x;
    const int lane = t & 63;
    const int wave = t >> 6;
    const int wm = wave >> 1, wn = wave & 1;
    const int q = lane >> 4, mr = lane & 15;

    const int m0 = blockIdx.y * 128;
    const int n0 = blockIdx.x * 128;
    const size_t cb = (size_t)blockIdx.z << 20;   // per-channel offset (B/C/P only)

    const unsigned short* Bh = Bhi + cb;
    const unsigned short* Bl = Blo + cb;          // unused if !SPLIT

    f32x4 acc[4][4];
#pragma unroll
    for (int i = 0; i < 4; ++i)
#pragma unroll
        for (int j = 0; j < 4; ++j) acc[i][j] = (f32x4){0.f, 0.f, 0.f, 0.f};

    // tril A: A[h,k]==0 for k>h; rows in this block are <= m0+127
    const int kEnd = TRIL ? ((m0 + 128 < 1024) ? m0 + 128 : 1024) : 1024;

    for (int k0 = 0; k0 < kEnd; k0 += 32) {
        __syncthreads();
        stage_tile(Ahi, m0, k0, ldsAhi, t);
        stage_tile(Bh,  n0, k0, ldsBhi, t);
        if constexpr (SPLIT) {
            stage_tile(Alo, m0, k0, ldsAlo, t);
            stage_tile(Bl,  n0, k0, ldsBlo, t);
        }
        __syncthreads();   // compiler emits s_waitcnt vmcnt(0) before s_barrier

        bf16x8 aH[4], bH[4], aL[4], bL[4];
#pragma unroll
        for (int i = 0; i < 4; ++i) {
            aH[i] = read_frag(ldsAhi, wm * 64 + i * 16 + mr, q);
            bH[i] = read_frag(ldsBhi, wn * 64 + i * 16 + mr, q);
            if constexpr (SPLIT) {
                aL[i] = read_frag(ldsAlo, wm * 64 + i * 16 + mr, q);
                bL[i] = read_frag(ldsBlo, wn * 64 + i * 16 + mr, q);
            }
        }
#pragma unroll
        for (int i = 0; i < 4; ++i)
#pragma unroll
            for (int j = 0; j < 4; ++j) {
                if constexpr (SPLIT) {
                    acc[i][j] = __builtin_amdgcn_mfma_f32_16x16x32_bf16(aL[i], bH[j], acc[i][j], 0, 0, 0);
                    acc[i][j] = __builtin_amdgcn_mfma_f32_16x16x32_bf16(aH[i], bL[j], acc[i][j], 0, 0, 0);
                }
                acc[i][j] = __builtin_amdgcn_mfma_f32_16x16x32_bf16(aH[i], bH[j], acc[i][j], 0, 0, 0);
            }
    }

    // C/D layout (m89/m91-verified): col = lane&15, row = (lane>>4)*4 + reg
#pragma unroll
    for (int i = 0; i < 4; ++i) {
        const int gmBase = m0 + wm * 64 + i * 16 + q * 4;
#pragma unroll
        for (int j = 0; j < 4; ++j) {
            const int gn = n0 + wn * 64 + j * 16 + mr;
#pragma unroll
            for (int r4 = 0; r4 < 4; ++r4) {
                const int gm = gmBase + r4;
                const size_t off = cb + ((size_t)gm << 10) + gn;
                float v = acc[i][j][r4];
                if constexpr (EPI == 0) {
                    O1[off] = f2bf(actf(v));
                } else if constexpr (EPI == 1) {
                    v = actf(v + bias[gm]);
                    const unsigned short hi = f2bf(v);
                    O1[off] = hi;
                    O2[off] = f2bf(v - bf2f(hi));
                } else {
                    v = actf(v + bias[gm]);
                    v += bf2f(Phi[off]) + bf2f(Plo[off]);
                    Of[off] = v;                      // float32 store
                }
            }
        }
    }
}

// Wp_eff = tril(Wp) with diag -> clamp(diag,0,1) + Wp_diag; split hi/lo.
// Wzp split hi/lo.  p_lin_w / z_lin_w plain bf16 (layout [j][i], K-contig).
__global__ void prep_weights(const float* __restrict__ Wp, const float* __restrict__ Wpd,
                             const float* __restrict__ Wzp,
                             const float* __restrict__ plw, const float* __restrict__ zlw,
                             unsigned short* __restrict__ WpHi, unsigned short* __restrict__ WpLo,
                             unsigned short* __restrict__ WzHi, unsigned short* __restrict__ WzLo,
                             unsigned short* __restrict__ plw16, unsigned short* __restrict__ zlw16) {
    const int idx = blockIdx.x * 256 + threadIdx.x;   // 0..1M-1
    const int h = idx >> 10, k = idx & 1023;
    float v = (k < h) ? Wp[idx] : 0.f;
    if (k == h) v = fminf(1.f, fmaxf(0.f, Wp[idx])) + Wpd[h];
    unsigned short hi = f2bf(v);
    WpHi[idx] = hi; WpLo[idx] = f2bf(v - bf2f(hi));
    const float wz = Wzp[idx];
    hi = f2bf(wz);
    WzHi[idx] = hi; WzLo[idx] = f2bf(wz - bf2f(hi));
    plw16[idx] = f2bf(plw[idx]);
    zlw16[idx] = f2bf(zlw[idx]);
}

// pSetT[c][i][h] = x[c][h][i] * act(p_mask[h][i]), split hi/lo. LDS-tiled transpose.
__global__ void prep_pset(const float* __restrict__ x, const float* __restrict__ pmask,
                          unsigned short* __restrict__ Thi, unsigned short* __restrict__ Tlo) {
    __shared__ float tile[32][33];
    const int tx = threadIdx.x, ty = threadIdx.y;     // 32 x 8
    const int i0 = blockIdx.x * 32, h0 = blockIdx.y * 32;
    const size_t cb = (size_t)blockIdx.z << 20;
#pragma unroll
    for (int s = 0; s < 4; ++s) {
        const int hh = ty + s * 8;
        const size_t gi = ((size_t)(h0 + hh) << 10) + i0 + tx;
        tile[hh][tx] = x[cb + gi] * actf(pmask[gi]);
    }
    __syncthreads();
#pragma unroll
    for (int s = 0; s < 4; ++s) {
        const int ii = ty + s * 8;
        const float v = tile[tx][ii];
        const size_t go = cb + ((size_t)(i0 + ii) << 10) + h0 + tx;
        const unsigned short hi = f2bf(v);
        Thi[go] = hi;
        Tlo[go] = f2bf(v - bf2f(hi));
    }
}

// out[c][h][j] = inT[c][j][h]  (float32)
__global__ void transpose_out(const float* __restrict__ inT,
                              float* __restrict__ out) {
    __shared__ float tile[32][33];
    const int tx = threadIdx.x, ty = threadIdx.y;     // 32 x 8
    const int h0 = blockIdx.x * 32, j0 = blockIdx.y * 32;
    const size_t cb = (size_t)blockIdx.z << 20;
#pragma unroll
    for (int s = 0; s < 4; ++s) {
        const int jj = ty + s * 8;
        tile[jj][tx] = inT[cb + ((size_t)(j0 + jj) << 10) + h0 + tx];
    }
    __syncthreads();
#pragma unroll
    for (int s = 0; s < 4; ++s) {
        const int hh = ty + s * 8;
        out[cb + ((size_t)(h0 + hh) << 10) + j0 + tx] = tile[tx][hh];
    }
}

extern "C" void kernel_launch(void* const* d_in, const int* in_sizes, int n_in,
                              void* d_out, int out_size, void* d_ws, size_t ws_size,
                              hipStream_t stream) {
    const float* x     = (const float*)d_in[0];
    const float* pmask = (const float*)d_in[1];
    const float* Wp    = (const float*)d_in[2];
    const float* Wpd   = (const float*)d_in[3];
    const float* Wzp   = (const float*)d_in[4];
    const float* plw   = (const float*)d_in[5];
    const float* plb   = (const float*)d_in[6];
    const float* zlw   = (const float*)d_in[7];
    const float* zlb   = (const float*)d_in[8];
    float* out = (float*)d_out;                     // FLOAT32 output

    char* w = (char*)d_ws;
    const size_t SZ = 134217728ull;                 // 64*1024*1024 bf16 = 128 MiB
    unsigned short* pSetT_hi = (unsigned short*)(w);
    unsigned short* pSetT_lo = (unsigned short*)(w + SZ);
    unsigned short* pT_hi    = (unsigned short*)(w + 2 * SZ);
    unsigned short* pT_lo    = (unsigned short*)(w + 3 * SZ);
    unsigned short* tA       = (unsigned short*)(w + 4 * SZ);  // act_t; reused as act_z
    float*          outT     = (float*)(w);                    // f32, reuses pSetT hi+lo (256 MiB)
    unsigned short* wts      = (unsigned short*)(w + 5 * SZ);
    unsigned short* WpHi = wts;
    unsigned short* WpLo = wts + 1 * 1048576;
    unsigned short* WzHi = wts + 2 * 1048576;
    unsigned short* WzLo = wts + 3 * 1048576;
    unsigned short* plw16 = wts + 4 * 1048576;
    unsigned short* zlw16 = wts + 5 * 1048576;

    const dim3 gW(4096), bW(256);
    const dim3 gT(32, 32, 64), bT(32, 8);
    const dim3 gG(8, 8, 64), bG(256);

    prep_weights<<<gW, bW, 0, stream>>>(Wp, Wpd, Wzp, plw, zlw,
                                        WpHi, WpLo, WzHi, WzLo, plw16, zlw16);
    prep_pset<<<gT, bT, 0, stream>>>(x, pmask, pSetT_hi, pSetT_lo);

    // mm1: act_t[c][h][i] = act( sum_k Wp_eff[h,k] * pSetT[c][i][k] )   [split, tril]
    gemm_tn<true, 0, true><<<gG, bG, 0, stream>>>(
        WpHi, WpLo, pSetT_hi, pSetT_lo, nullptr, nullptr, nullptr, tA, nullptr, nullptr);

    // mm2 (transposed): pT[c][j][h] = act( sum_i plw[j,i] * act_t[c][h][i] + b_p[j] ), split store
    gemm_tn<false, 1, false><<<gG, bG, 0, stream>>>(
        plw16, nullptr, tA, nullptr, plb, nullptr, nullptr, pT_hi, pT_lo, nullptr);

    // mm3: act_z[c][h][i] = act( sum_k Wzp[h,k] * pT[c][i][k] )   [split]
    gemm_tn<true, 0, false><<<gG, bG, 0, stream>>>(
        WzHi, WzLo, pT_hi, pT_lo, nullptr, nullptr, nullptr, tA, nullptr, nullptr);

    // mm4 (transposed): outT[c][j][h] = act( sum_i zlw[j,i]*act_z[c][h][i] + b_z[j] ) + pT[c][j][h]
    gemm_tn<false, 2, false><<<gG, bG, 0, stream>>>(
        zlw16, nullptr, tA, nullptr, zlb, pT_hi, pT_lo, nullptr, nullptr, outT);

    // restore [c][h][j]  (f32 -> f32 into d_out)
    transpose_out<<<gT, bT, 0, stream>>>(outT, out);
}